// Round 19
// baseline (535.081 us; speedup 1.0000x reference)
//
#include <hip/hip_runtime.h>
#include <hip/hip_bf16.h>
#include <math.h>

#define BGR 64
#define ECAP 16000
#define EMAX 1024000

typedef _Float16 f16x8 __attribute__((ext_vector_type(8)));
typedef float f32x4 __attribute__((ext_vector_type(4)));

// ---------------- pnorm x3 ----------------
__global__ __launch_bounds__(128) void pnorm3_kernel(const float* __restrict__ p1,
                              const float* __restrict__ p2,
                              const float* __restrict__ p3, float* __restrict__ out) {
    __shared__ float buf[128];
    int t = threadIdx.x, b = blockIdx.x;
    const float* p = (b == 0) ? p1 : (b == 1) ? p2 : p3;
    buf[t] = p[t] * p[t];
    __syncthreads();
    for (int off = 64; off; off >>= 1) {
        if (t < off) buf[t] += buf[t + off];
        __syncthreads();
    }
    if (t == 0) out[b] = sqrtf(buf[0]);
}

// ---------------- weight split: f32 [k][n] -> f16 hi/lo chunk-major ----------------
struct WP { const float* w[9]; };

__global__ void wsplit_kernel(WP wp, _Float16* __restrict__ out) {
    int mat = blockIdx.x;
    const float* __restrict__ w = wp.w[mat];
    _Float16* __restrict__ dst = out + (size_t)mat * 32768;
    for (int e = threadIdx.x; e < 2048; e += 256) {
        int n = e >> 4;
        int kb = (e & 15) * 8;
        f16x8 hi, lo;
#pragma unroll
        for (int j = 0; j < 8; j++) {
            float v = w[(kb + j) * 128 + n];
            _Float16 h = (_Float16)v;
            hi[j] = h;
            lo[j] = (_Float16)((v - (float)h) * 2048.0f);
        }
        int ks = kb >> 5, kg = (kb >> 3) & 3;
        *(f16x8*)(dst + ((((ks * 2 + 0) * 4 + kg) * 128 + n) * 8)) = hi;
        *(f16x8*)(dst + ((((ks * 2 + 1) * 4 + kg) * 128 + n) * 8)) = lo;
    }
}

// ---------------- per-graph CSR build: count + LDS scan + LDS-cursor scatter ----------
__global__ __launch_bounds__(1024) void build_kernel(
    const int* __restrict__ src, const int* __restrict__ dst,
    const int* __restrict__ gcnt, int fixedcnt, int npg,
    int2* __restrict__ rowdeg, float* __restrict__ dinv, int2* __restrict__ edata) {
    __shared__ int cnt[1024];
    __shared__ int scn[1024];
    __shared__ float sdinv[1024];
    int g = blockIdx.x, t = threadIdx.x;
    int E = gcnt ? gcnt[g] : fixedcnt;
    int ebase = g * ECAP;
    int gnb = g * npg;
    cnt[t] = 0;
    __syncthreads();
    for (int i = t; i < E; i += 1024)
        atomicAdd(&cnt[dst[ebase + i] - gnb], 1);
    __syncthreads();
    int myc = (t < npg) ? cnt[t] : 0;
    scn[t] = myc;
    __syncthreads();
    for (int off = 1; off < 1024; off <<= 1) {
        int v = (t >= off) ? scn[t - off] : 0;
        __syncthreads();
        scn[t] += v;
        __syncthreads();
    }
    int excl = scn[t] - myc;
    if (t < npg) {
        float dv = rsqrtf((float)myc + 1.0f);
        rowdeg[gnb + t] = make_int2(ebase + excl, myc);
        dinv[gnb + t] = dv;
        sdinv[t] = dv;
        scn[t] = excl;                    // becomes LDS cursor
    }
    __syncthreads();
    for (int i = t; i < E; i += 1024) {
        int s = src[ebase + i];
        int d = dst[ebase + i];
        int sl = s - gnb, dl = d - gnb;
        int pos = atomicAdd(&scn[dl], 1);
        edata[ebase + pos] = make_int2(s, __float_as_int(sdinv[sl] * sdinv[dl]));
    }
}

// ---------------- fused 3-branch MFMA GEMM (f16 split, f32-equivalent accuracy) ----------
__global__ __launch_bounds__(256) void gemm3m_kernel(
    const float* __restrict__ x, const _Float16* __restrict__ wsp,
    const float* __restrict__ b0, const float* __restrict__ b1, const float* __restrict__ b2,
    float* __restrict__ out) {
    __shared__ _Float16 ws[2][16384] __attribute__((aligned(16)));
    const int tid = threadIdx.x;
    const int wave = tid >> 6;
    const int lane = tid & 63;
    const int l15 = lane & 15;
    const int kg = lane >> 4;          // 0..3
    const long base = (long)blockIdx.x * 64;
    const int m = wave * 16 + l15;     // row within block tile

    float4 xrow[8];
    const float4* xg = (const float4*)(x + (base + m) * 128);
#pragma unroll
    for (int q = 0; q < 8; q++) xrow[q] = xg[(q >> 1) * 8 + kg * 2 + (q & 1)];

    auto stageH = [&](int s, int buf) {
#pragma unroll
        for (int t = 0; t < 8; t++) {
            int u = tid + t * 256;
            __builtin_amdgcn_global_load_lds(
                (const __attribute__((address_space(1))) unsigned int*)(wsp + (size_t)s * 16384 + u * 8),
                (__attribute__((address_space(3))) unsigned int*)(&ws[buf][u * 8]),
                16, 0, 0);
        }
    };

    float tot[8][4];
#pragma unroll
    for (int nt = 0; nt < 8; nt++)
#pragma unroll
        for (int r = 0; r < 4; r++) tot[nt][r] = 0.f;

    f32x4 acc_h[8], acc_m[8];
    stageH(0, 0);

    for (int s = 0; s < 6; s++) {
        const int j = s >> 1;
        __syncthreads();
        if (s < 5) stageH(s + 1, (s & 1) ^ 1);

        if ((s & 1) == 0) {
#pragma unroll
            for (int nt = 0; nt < 8; nt++) {
                acc_h[nt] = (f32x4){0.f, 0.f, 0.f, 0.f};
                acc_m[nt] = (f32x4){0.f, 0.f, 0.f, 0.f};
            }
        }

        const _Float16* wbase = &ws[s & 1][0];
#pragma unroll
        for (int ksl = 0; ksl < 2; ksl++) {
            const int ks = (s & 1) * 2 + ksl;
            float ev[8] = {xrow[ks * 2].x, xrow[ks * 2].y, xrow[ks * 2].z, xrow[ks * 2].w,
                           xrow[ks * 2 + 1].x, xrow[ks * 2 + 1].y, xrow[ks * 2 + 1].z, xrow[ks * 2 + 1].w};
            f16x8 ah, al;
#pragma unroll
            for (int i = 0; i < 8; i++) {
                _Float16 h = (_Float16)ev[i];
                ah[i] = h;
                al[i] = (_Float16)((ev[i] - (float)h) * 2048.0f);
            }
            const _Float16* wb = wbase + ksl * 8192;
            const int nb = kg * 1024 + l15 * 8;
            f16x8 bh[8], bl[8];
#pragma unroll
            for (int nt = 0; nt < 8; nt++) {
                bh[nt] = *(const f16x8*)(wb + nb + nt * 128);
                bl[nt] = *(const f16x8*)(wb + 4096 + nb + nt * 128);
            }
#pragma unroll
            for (int nt = 0; nt < 8; nt++)
                acc_h[nt] = __builtin_amdgcn_mfma_f32_16x16x32_f16(ah, bh[nt], acc_h[nt], 0, 0, 0);
#pragma unroll
            for (int nt = 0; nt < 8; nt++)
                acc_m[nt] = __builtin_amdgcn_mfma_f32_16x16x32_f16(ah, bl[nt], acc_m[nt], 0, 0, 0);
#pragma unroll
            for (int nt = 0; nt < 8; nt++)
                acc_m[nt] = __builtin_amdgcn_mfma_f32_16x16x32_f16(al, bh[nt], acc_m[nt], 0, 0, 0);
        }

        if (s & 1) {
            const float* bb = (j == 0) ? b0 : (j == 1) ? b1 : b2;
#pragma unroll
            for (int nt = 0; nt < 8; nt++) {
                float bv = bb[nt * 16 + l15];
#pragma unroll
                for (int r = 0; r < 4; r++)
                    tot[nt][r] += fmaxf(acc_h[nt][r] + acc_m[nt][r] * (1.0f / 2048.0f) + bv, 0.f);
            }
        }
    }

    float* op = out + (base + wave * 16 + kg * 4) * 128 + l15;
#pragma unroll
    for (int nt = 0; nt < 8; nt++)
#pragma unroll
        for (int r = 0; r < 4; r++) op[r * 128 + nt * 16] = tot[nt][r];
}

// ---------------- propagation (+optional fused score) ----------------
// FULL-WAVE per node (64 lanes x 8B): T = ceil(deg/16) (vs ceil(max2/16)) ->
// ~20% fewer padded gather slots; float2 payload halves in-flight VGPRs.
template <int SC>
__global__ __launch_bounds__(256, 4) void prop_t(
    const float* __restrict__ hin, float* __restrict__ hout,
    const int2* __restrict__ rowdeg, const int2* __restrict__ edata,
    const float* __restrict__ dinv,
    const float* __restrict__ p, const float* __restrict__ pn, float* __restrict__ score) {
    int per = gridDim.x >> 3;
    int b = blockIdx.x;
    int sb = (b & 7) * per + (b >> 3);          // XCD swizzle
    int wave = threadIdx.x >> 6;
    int lane = threadIdx.x & 63;
    int node = sb * 4 + wave;

    const char* hb = (const char*)hin;
    const unsigned loff = (unsigned)lane * 8u;

    float2 hv = *(const float2*)(hb + (size_t)node * 512 + loff);
    float di = dinv[node];
    float selfc = 1.0f + di * di;
    float ax = hv.x * selfc, ay = hv.y * selfc;

    int2 rd = rowdeg[node];
    int e0 = rd.x;
    int dg = rd.y;
    int e1 = e0 + dg;
    int T = (dg + 15) >> 4;

    for (int t = 0; t < T; ++t) {
        int ee = e0 + t * 16 + (lane & 15);
        int ec = ee < e1 - 1 ? ee : e1 - 1;
        ec = ec < e0 ? e0 : ec;
        int2 md = edata[ec];
        bool val = ee < e1;
        int ci = val ? md.x : 0;
        int wi = val ? md.y : 0;
        float2 g[16];
        float w[16];
#pragma unroll
        for (int j = 0; j < 16; ++j) {
            int idx = __builtin_amdgcn_ds_bpermute(j * 4, ci);
            int wj = __builtin_amdgcn_ds_bpermute(j * 4, wi);
            w[j] = __int_as_float(wj);
            g[j] = *(const float2*)(hb + (unsigned)idx * 512u + loff);
        }
        __builtin_amdgcn_sched_barrier(0);
#pragma unroll
        for (int j = 0; j < 16; ++j) {
            ax += w[j] * g[j].x;
            ay += w[j] * g[j].y;
        }
    }

    *(float2*)((char*)hout + (size_t)node * 512 + loff) = make_float2(ax, ay);

    if (SC) {
        float2 pv = ((const float2*)p)[lane];
        float v = ax * pv.x + ay * pv.y;
        v += __shfl_xor(v, 32);
        v += __shfl_xor(v, 16);
        v += __shfl_xor(v, 8);
        v += __shfl_xor(v, 4);
        v += __shfl_xor(v, 2);
        v += __shfl_xor(v, 1);
        if (lane == 0) score[node] = v / pn[0];
    }
}

// ---------------- top-k pool: 1024-thread key-packed bitonic sort ----------------
__global__ __launch_bounds__(1024) void pool_kernel(const float* __restrict__ score, int npg, int k,
                            int* __restrict__ perm, float* __restrict__ gate,
                            int* __restrict__ remap) {
    __shared__ unsigned long long skey[1024];
    int b = blockIdx.x, t = threadIdx.x;
    float v = (t < npg) ? score[b * npg + t] : -INFINITY;
    unsigned ub = __float_as_uint(v);
    unsigned asc = ub ^ ((ub >> 31) ? 0xFFFFFFFFu : 0x80000000u);  // ascending uint map
    unsigned desc = ~asc;                                          // descending
    skey[t] = ((unsigned long long)desc << 32) | (unsigned)t;
    __syncthreads();
    for (int ksz = 2; ksz <= 1024; ksz <<= 1) {
        for (int j = ksz >> 1; j > 0; j >>= 1) {
            int l = t ^ j;
            if (l > t) {
                unsigned long long a = skey[t], c = skey[l];
                bool up = ((t & ksz) == 0);
                if (up ? (a > c) : (a < c)) { skey[t] = c; skey[l] = a; }
            }
            __syncthreads();
        }
    }
    if (t < k) {
        int idx = (int)(skey[t] & 0xFFFFFFFFu);
        int oldg = b * npg + idx;
        int newg = b * k + t;
        perm[newg] = oldg;
        gate[newg] = tanhf(score[oldg]);
        remap[oldg] = newg;
    } else if (t < npg) {
        int idx = (int)(skey[t] & 0xFFFFFFFFu);
        remap[b * npg + idx] = -1;
    }
}

// ---------------- gather new_x = h[perm] * gate (massively parallel) ----------------
__global__ void newx_kernel(const float* __restrict__ h, const int* __restrict__ perm,
                            const float* __restrict__ gate, float* __restrict__ xo) {
    int m = blockIdx.x * 4 + (threadIdx.x >> 6);
    int lane = threadIdx.x & 63;
    int old = perm[m];
    float g = gate[m];
    float2 v = ((const float2*)h)[old * 64 + lane];
    ((float2*)xo)[m * 64 + lane] = make_float2(v.x * g, v.y * g);
}

// ---------------- readout: rsum[b] (=|+=) [max over k ; mean over k] ----------------
__global__ __launch_bounds__(512) void readout_kernel(const float* __restrict__ x,
                                                      float* __restrict__ rsum, int k,
                                                      int first) {
    __shared__ float smx[4][128], ssm[4][128];
    int b = blockIdx.x, t = threadIdx.x;
    int f = t & 127, c = t >> 7;
    int rows = k >> 2;
    const float* base = x + (size_t)b * k * 128 + (size_t)c * rows * 128 + f;
    float mx = -INFINITY, sm = 0.f;
#pragma unroll 8
    for (int j = 0; j < rows; j++) {
        float v = base[(size_t)j * 128];
        mx = fmaxf(mx, v);
        sm += v;
    }
    smx[c][f] = mx;
    ssm[c][f] = sm;
    __syncthreads();
    if (c == 0) {
        float m2 = fmaxf(fmaxf(smx[0][f], smx[1][f]), fmaxf(smx[2][f], smx[3][f]));
        float s2 = (ssm[0][f] + ssm[1][f] + ssm[2][f] + ssm[3][f]) / (float)k;
        if (first) {
            rsum[b * 256 + f] = m2;
            rsum[b * 256 + 128 + f] = s2;
        } else {
            rsum[b * 256 + f] += m2;
            rsum[b * 256 + 128 + f] += s2;
        }
    }
}

// ---------------- per-graph edge compact (keeps per-graph segments) ----------------
__global__ __launch_bounds__(1024) void compact_kernel(
    const int* __restrict__ src, const int* __restrict__ dst,
    const int* __restrict__ gcntIn, int fixedIn, const int* __restrict__ remap,
    int* __restrict__ so, int* __restrict__ dd, int* __restrict__ gcntOut) {
    __shared__ int wsum[16];
    __shared__ int runbase;
    int g = blockIdx.x, t = threadIdx.x;
    int wave = t >> 6, lane = t & 63;
    int E = gcntIn ? gcntIn[g] : fixedIn;
    int ebase = g * ECAP;
    if (t == 0) runbase = 0;
    __syncthreads();
    for (int i0 = 0; i0 < E; i0 += 1024) {
        int i = i0 + t;
        bool v = false;
        int s = 0, d = 0;
        if (i < E) {
            s = remap[src[ebase + i]];
            d = remap[dst[ebase + i]];
            v = ((s | d) >= 0);
        }
        unsigned long long m = __ballot(v);
        int before = __popcll(m & ((1ULL << lane) - 1ULL));
        if (lane == 0) wsum[wave] = __popcll(m);
        __syncthreads();
        if (t == 0) {
            int tot = 0;
#pragma unroll
            for (int w2 = 0; w2 < 16; w2++) { int c = wsum[w2]; wsum[w2] = runbase + tot; tot += c; }
            runbase += tot;
        }
        __syncthreads();
        if (v) {
            int pos = ebase + wsum[wave] + before;
            so[pos] = s;
            dd[pos] = d;
        }
        __syncthreads();
    }
    if (t == 0) gcntOut[g] = runbase;
}

// ---------------- fused final MLP + log_softmax ----------------
__global__ void mlp_kernel(const float* __restrict__ rsum,
                           const float* __restrict__ w1, const float* __restrict__ b1,
                           const float* __restrict__ w2, const float* __restrict__ b2,
                           const float* __restrict__ w3, const float* __restrict__ b3,
                           float* __restrict__ out) {
    __shared__ float z0[256], z1l[128], z2l[64], lg[10], ls;
    int b = blockIdx.x, t = threadIdx.x;   // 128 threads
    z0[t] = rsum[b * 256 + t];
    z0[t + 128] = rsum[b * 256 + 128 + t];
    __syncthreads();
    float acc = b1[t];
    for (int k = 0; k < 256; k++) acc += z0[k] * w1[k * 128 + t];
    z1l[t] = fmaxf(acc, 0.f);
    __syncthreads();
    if (t < 64) {
        acc = b2[t];
        for (int k = 0; k < 128; k++) acc += z1l[k] * w2[k * 64 + t];
        z2l[t] = fmaxf(acc, 0.f);
    }
    __syncthreads();
    if (t < 10) {
        acc = b3[t];
        for (int k = 0; k < 64; k++) acc += z2l[k] * w3[k * 10 + t];
        lg[t] = acc;
    }
    __syncthreads();
    if (t == 0) {
        float mx = lg[0];
        for (int c = 1; c < 10; c++) mx = fmaxf(mx, lg[c]);
        float s = 0.f;
        for (int c = 0; c < 10; c++) s += expf(lg[c] - mx);
        ls = mx + logf(s);
    }
    __syncthreads();
    if (t < 10) out[b * 10 + t] = lg[t] - ls;
}

// =====================================================================
extern "C" void kernel_launch(void* const* d_in, const int* in_sizes, int n_in,
                              void* d_out, int out_size, void* d_ws, size_t ws_size,
                              hipStream_t stream) {
    char* ws = (char*)d_ws;
    size_t off = 0;
    auto alloc = [&](size_t bytes) -> void* {
        void* p = ws + off;
        off += (bytes + 255) & ~(size_t)255;
        return p;
    };
    float* hA = (float*)alloc(64000UL * 128 * 4);
    float* hB = (float*)alloc(64000UL * 128 * 4);
    float* score = (float*)alloc(64000UL * 4);
    float* dinvb = (float*)alloc(64000UL * 4);
    int2* rowdeg = (int2*)alloc(64000UL * 8);
    int2* edata = (int2*)alloc((size_t)EMAX * 8);
    int* srcA = (int*)alloc((size_t)EMAX * 4);
    int* dstA = (int*)alloc((size_t)EMAX * 4);
    int* srcB = (int*)alloc((size_t)EMAX * 4);
    int* dstB = (int*)alloc((size_t)EMAX * 4);
    int* perm = (int*)alloc(51200UL * 4);
    float* gate = (float*)alloc(51200UL * 4);
    int* remap = (int*)alloc(64000UL * 4);
    float* rsum = (float*)alloc(64UL * 256 * 4);
    _Float16* wsall = (_Float16*)alloc(9UL * 32768 * 2);
    float* pnorm = (float*)alloc(256);
    int* gA = (int*)alloc(256);
    int* gB = (int*)alloc(256);
    (void)ws_size;  // requires ~94 MB

    const float* x0 = (const float*)d_in[0];
    const int* src0 = (const int*)d_in[1];
    const int* dst0 = (const int*)d_in[2];

    pnorm3_kernel<<<3, 128, 0, stream>>>((const float*)d_in[27], (const float*)d_in[28],
                                         (const float*)d_in[29], pnorm);

    WP wp;
    wp.w[0] = (const float*)d_in[3];  wp.w[1] = (const float*)d_in[5];  wp.w[2] = (const float*)d_in[7];
    wp.w[3] = (const float*)d_in[9];  wp.w[4] = (const float*)d_in[11]; wp.w[5] = (const float*)d_in[13];
    wp.w[6] = (const float*)d_in[15]; wp.w[7] = (const float*)d_in[17]; wp.w[8] = (const float*)d_in[19];
    wsplit_kernel<<<9, 256, 0, stream>>>(wp, wsall);

    auto run_layer = [&](int n, int npg, int k, const float* x, int layer,
                         const int* esrc, const int* edst, const int* gcnt,
                         const float* ba, const float* bb, const float* bc,
                         const float* p, const float* pn,
                         int* so, int* ddst, int* gout) {
        build_kernel<<<BGR, 1024, 0, stream>>>(esrc, edst, gcnt, ECAP, npg,
                                               rowdeg, dinvb, edata);
        gemm3m_kernel<<<n / 64, 256, 0, stream>>>(x, wsall + (size_t)layer * 3 * 32768,
                                                  ba, bb, bc, hA);
        prop_t<0><<<n / 4, 256, 0, stream>>>(hA, hB, rowdeg, edata, dinvb,
                                             nullptr, nullptr, nullptr);
        prop_t<1><<<n / 4, 256, 0, stream>>>(hB, hA, rowdeg, edata, dinvb,
                                             p, pn, score);
        pool_kernel<<<BGR, 1024, 0, stream>>>(score, npg, k, perm, gate, remap);
        newx_kernel<<<(BGR * k) / 4, 256, 0, stream>>>(hA, perm, gate, hB);
        readout_kernel<<<BGR, 512, 0, stream>>>(hB, rsum, k, layer == 0 ? 1 : 0);
        if (gout)
            compact_kernel<<<BGR, 1024, 0, stream>>>(esrc, edst, gcnt, ECAP, remap,
                                                     so, ddst, gout);
    };

    run_layer(64000, 1000, 800, x0, 0, src0, dst0, nullptr,
              (const float*)d_in[4], (const float*)d_in[6], (const float*)d_in[8],
              (const float*)d_in[27], pnorm + 0, srcA, dstA, gA);

    run_layer(51200, 800, 640, hB, 1, srcA, dstA, gA,
              (const float*)d_in[10], (const float*)d_in[12], (const float*)d_in[14],
              (const float*)d_in[28], pnorm + 1, srcB, dstB, gB);

    run_layer(40960, 640, 512, hB, 2, srcB, dstB, gB,
              (const float*)d_in[16], (const float*)d_in[18], (const float*)d_in[20],
              (const float*)d_in[29], pnorm + 2, nullptr, nullptr, nullptr);

    mlp_kernel<<<64, 128, 0, stream>>>(rsum, (const float*)d_in[21], (const float*)d_in[22],
                                       (const float*)d_in[23], (const float*)d_in[24],
                                       (const float*)d_in[25], (const float*)d_in[26],
                                       (float*)d_out);
}

// Round 20
// 448.542 us; speedup vs baseline: 1.1929x; 1.1929x over previous
//
#include <hip/hip_runtime.h>
#include <hip/hip_bf16.h>
#include <math.h>

#define BGR 64
#define ECAP 16000
#define EMAX 1024000

typedef _Float16 f16x8 __attribute__((ext_vector_type(8)));
typedef float f32x4 __attribute__((ext_vector_type(4)));

// ---------------- pnorm x3 ----------------
__global__ __launch_bounds__(128) void pnorm3_kernel(const float* __restrict__ p1,
                              const float* __restrict__ p2,
                              const float* __restrict__ p3, float* __restrict__ out) {
    __shared__ float buf[128];
    int t = threadIdx.x, b = blockIdx.x;
    const float* p = (b == 0) ? p1 : (b == 1) ? p2 : p3;
    buf[t] = p[t] * p[t];
    __syncthreads();
    for (int off = 64; off; off >>= 1) {
        if (t < off) buf[t] += buf[t + off];
        __syncthreads();
    }
    if (t == 0) out[b] = sqrtf(buf[0]);
}

// ---------------- weight split: f32 [k][n] -> f16 hi/lo chunk-major ----------------
struct WP { const float* w[9]; };

__global__ void wsplit_kernel(WP wp, _Float16* __restrict__ out) {
    int mat = blockIdx.x;
    const float* __restrict__ w = wp.w[mat];
    _Float16* __restrict__ dst = out + (size_t)mat * 32768;
    for (int e = threadIdx.x; e < 2048; e += 256) {
        int n = e >> 4;
        int kb = (e & 15) * 8;
        f16x8 hi, lo;
#pragma unroll
        for (int j = 0; j < 8; j++) {
            float v = w[(kb + j) * 128 + n];
            _Float16 h = (_Float16)v;
            hi[j] = h;
            lo[j] = (_Float16)((v - (float)h) * 2048.0f);
        }
        int ks = kb >> 5, kg = (kb >> 3) & 3;
        *(f16x8*)(dst + ((((ks * 2 + 0) * 4 + kg) * 128 + n) * 8)) = hi;
        *(f16x8*)(dst + ((((ks * 2 + 1) * 4 + kg) * 128 + n) * 8)) = lo;
    }
}

// ---------------- per-graph CSR build: count + LDS scan + LDS-cursor scatter ----------
__global__ __launch_bounds__(1024) void build_kernel(
    const int* __restrict__ src, const int* __restrict__ dst,
    const int* __restrict__ gcnt, int fixedcnt, int npg,
    int2* __restrict__ rowdeg, float* __restrict__ dinv, int2* __restrict__ edata) {
    __shared__ int cnt[1024];
    __shared__ int scn[1024];
    __shared__ float sdinv[1024];
    int g = blockIdx.x, t = threadIdx.x;
    int E = gcnt ? gcnt[g] : fixedcnt;
    int ebase = g * ECAP;
    int gnb = g * npg;
    cnt[t] = 0;
    __syncthreads();
    for (int i = t; i < E; i += 1024)
        atomicAdd(&cnt[dst[ebase + i] - gnb], 1);
    __syncthreads();
    int myc = (t < npg) ? cnt[t] : 0;
    scn[t] = myc;
    __syncthreads();
    for (int off = 1; off < 1024; off <<= 1) {
        int v = (t >= off) ? scn[t - off] : 0;
        __syncthreads();
        scn[t] += v;
        __syncthreads();
    }
    int excl = scn[t] - myc;
    if (t < npg) {
        float dv = rsqrtf((float)myc + 1.0f);
        rowdeg[gnb + t] = make_int2(ebase + excl, myc);
        dinv[gnb + t] = dv;
        sdinv[t] = dv;
        scn[t] = excl;                    // becomes LDS cursor
    }
    __syncthreads();
    for (int i = t; i < E; i += 1024) {
        int s = src[ebase + i];
        int d = dst[ebase + i];
        int sl = s - gnb, dl = d - gnb;
        int pos = atomicAdd(&scn[dl], 1);
        edata[ebase + pos] = make_int2(s, __float_as_int(sdinv[sl] * sdinv[dl]));
    }
}

// ---------------- fused 3-branch MFMA GEMM (f16 split, f32-equivalent accuracy) ----------
__global__ __launch_bounds__(256) void gemm3m_kernel(
    const float* __restrict__ x, const _Float16* __restrict__ wsp,
    const float* __restrict__ b0, const float* __restrict__ b1, const float* __restrict__ b2,
    float* __restrict__ out) {
    __shared__ _Float16 ws[2][16384] __attribute__((aligned(16)));
    const int tid = threadIdx.x;
    const int wave = tid >> 6;
    const int lane = tid & 63;
    const int l15 = lane & 15;
    const int kg = lane >> 4;          // 0..3
    const long base = (long)blockIdx.x * 64;
    const int m = wave * 16 + l15;     // row within block tile

    float4 xrow[8];
    const float4* xg = (const float4*)(x + (base + m) * 128);
#pragma unroll
    for (int q = 0; q < 8; q++) xrow[q] = xg[(q >> 1) * 8 + kg * 2 + (q & 1)];

    auto stageH = [&](int s, int buf) {
#pragma unroll
        for (int t = 0; t < 8; t++) {
            int u = tid + t * 256;
            __builtin_amdgcn_global_load_lds(
                (const __attribute__((address_space(1))) unsigned int*)(wsp + (size_t)s * 16384 + u * 8),
                (__attribute__((address_space(3))) unsigned int*)(&ws[buf][u * 8]),
                16, 0, 0);
        }
    };

    float tot[8][4];
#pragma unroll
    for (int nt = 0; nt < 8; nt++)
#pragma unroll
        for (int r = 0; r < 4; r++) tot[nt][r] = 0.f;

    f32x4 acc_h[8], acc_m[8];
    stageH(0, 0);

    for (int s = 0; s < 6; s++) {
        const int j = s >> 1;
        __syncthreads();
        if (s < 5) stageH(s + 1, (s & 1) ^ 1);

        if ((s & 1) == 0) {
#pragma unroll
            for (int nt = 0; nt < 8; nt++) {
                acc_h[nt] = (f32x4){0.f, 0.f, 0.f, 0.f};
                acc_m[nt] = (f32x4){0.f, 0.f, 0.f, 0.f};
            }
        }

        const _Float16* wbase = &ws[s & 1][0];
#pragma unroll
        for (int ksl = 0; ksl < 2; ksl++) {
            const int ks = (s & 1) * 2 + ksl;
            float ev[8] = {xrow[ks * 2].x, xrow[ks * 2].y, xrow[ks * 2].z, xrow[ks * 2].w,
                           xrow[ks * 2 + 1].x, xrow[ks * 2 + 1].y, xrow[ks * 2 + 1].z, xrow[ks * 2 + 1].w};
            f16x8 ah, al;
#pragma unroll
            for (int i = 0; i < 8; i++) {
                _Float16 h = (_Float16)ev[i];
                ah[i] = h;
                al[i] = (_Float16)((ev[i] - (float)h) * 2048.0f);
            }
            const _Float16* wb = wbase + ksl * 8192;
            const int nb = kg * 1024 + l15 * 8;
            f16x8 bh[8], bl[8];
#pragma unroll
            for (int nt = 0; nt < 8; nt++) {
                bh[nt] = *(const f16x8*)(wb + nb + nt * 128);
                bl[nt] = *(const f16x8*)(wb + 4096 + nb + nt * 128);
            }
#pragma unroll
            for (int nt = 0; nt < 8; nt++)
                acc_h[nt] = __builtin_amdgcn_mfma_f32_16x16x32_f16(ah, bh[nt], acc_h[nt], 0, 0, 0);
#pragma unroll
            for (int nt = 0; nt < 8; nt++)
                acc_m[nt] = __builtin_amdgcn_mfma_f32_16x16x32_f16(ah, bl[nt], acc_m[nt], 0, 0, 0);
#pragma unroll
            for (int nt = 0; nt < 8; nt++)
                acc_m[nt] = __builtin_amdgcn_mfma_f32_16x16x32_f16(al, bh[nt], acc_m[nt], 0, 0, 0);
        }

        if (s & 1) {
            const float* bb = (j == 0) ? b0 : (j == 1) ? b1 : b2;
#pragma unroll
            for (int nt = 0; nt < 8; nt++) {
                float bv = bb[nt * 16 + l15];
#pragma unroll
                for (int r = 0; r < 4; r++)
                    tot[nt][r] += fmaxf(acc_h[nt][r] + acc_m[nt][r] * (1.0f / 2048.0f) + bv, 0.f);
            }
        }
    }

    float* op = out + (base + wave * 16 + kg * 4) * 128 + l15;
#pragma unroll
    for (int nt = 0; nt < 8; nt++)
#pragma unroll
        for (int r = 0; r < 4; r++) op[r * 128 + nt * 16] = tot[nt][r];
}

// ---------------- propagation (+optional fused score) ----------------
// Half-wave per node (float4/lane): 32 edges in flight per wave (MLP-optimal).
// ds_bpermute metadata broadcast on the DS pipe.
template <int SC>
__global__ __launch_bounds__(256, 4) void prop_t(
    const float* __restrict__ hin, float* __restrict__ hout,
    const int2* __restrict__ rowdeg, const int2* __restrict__ edata,
    const float* __restrict__ dinv,
    const float* __restrict__ p, const float* __restrict__ pn, float* __restrict__ score) {
    int per = gridDim.x >> 3;
    int b = blockIdx.x;
    int sb = (b & 7) * per + (b >> 3);          // XCD swizzle
    int wave = threadIdx.x >> 6;
    int lane = threadIdx.x & 63;
    int half = lane >> 5;
    int l31 = lane & 31;
    int node = sb * 8 + wave * 2 + half;
    int pbase = (lane & 32) << 2;               // bpermute byte base: half*128

    const char* hb = (const char*)hin;
    const unsigned loff = (unsigned)l31 * 16u;

    float4 hv = *(const float4*)(hb + (size_t)node * 512 + loff);
    float di = dinv[node];
    float selfc = 1.0f + di * di;
    float ax = hv.x * selfc, ay = hv.y * selfc, az = hv.z * selfc, aw = hv.w * selfc;

    int2 rd = rowdeg[node];
    int e0 = rd.x;
    int dg = rd.y;
    int e1 = e0 + dg;
    int degA = __builtin_amdgcn_readlane(dg, 0);
    int degB = __builtin_amdgcn_readlane(dg, 32);
    int dmax = degA > degB ? degA : degB;
    int T = (dmax + 15) >> 4;

    for (int t = 0; t < T; ++t) {
        int ee = e0 + t * 16 + (lane & 15);
        int ec = ee < e1 - 1 ? ee : e1 - 1;
        ec = ec < e0 ? e0 : ec;
        int2 md = edata[ec];
        bool val = ee < e1;
        int ci = val ? md.x : 0;
        int wi = val ? md.y : 0;
        float4 g[16];
        float w[16];
#pragma unroll
        for (int j = 0; j < 16; ++j) {
            int idx = __builtin_amdgcn_ds_bpermute(pbase + j * 4, ci);
            int wj = __builtin_amdgcn_ds_bpermute(pbase + j * 4, wi);
            w[j] = __int_as_float(wj);
            g[j] = *(const float4*)(hb + (unsigned)idx * 512u + loff);
        }
        __builtin_amdgcn_sched_barrier(0);
#pragma unroll
        for (int j = 0; j < 16; ++j) {
            ax += w[j] * g[j].x;
            ay += w[j] * g[j].y;
            az += w[j] * g[j].z;
            aw += w[j] * g[j].w;
        }
    }

    *(float4*)((char*)hout + (size_t)node * 512 + loff) = make_float4(ax, ay, az, aw);

    if (SC) {
        float4 pv = ((const float4*)p)[l31];
        float v = ax * pv.x + ay * pv.y + az * pv.z + aw * pv.w;
        v += __shfl_xor(v, 16);
        v += __shfl_xor(v, 8);
        v += __shfl_xor(v, 4);
        v += __shfl_xor(v, 2);
        v += __shfl_xor(v, 1);
        if (l31 == 0) score[node] = v / pn[0];
    }
}

// ---------------- top-k pool: 1024-thread key-packed bitonic sort ----------------
__global__ __launch_bounds__(1024) void pool_kernel(const float* __restrict__ score, int npg, int k,
                            int* __restrict__ perm, float* __restrict__ gate,
                            int* __restrict__ remap) {
    __shared__ unsigned long long skey[1024];
    int b = blockIdx.x, t = threadIdx.x;
    float v = (t < npg) ? score[b * npg + t] : -INFINITY;
    unsigned ub = __float_as_uint(v);
    unsigned asc = ub ^ ((ub >> 31) ? 0xFFFFFFFFu : 0x80000000u);  // ascending uint map
    unsigned desc = ~asc;                                          // descending
    skey[t] = ((unsigned long long)desc << 32) | (unsigned)t;
    __syncthreads();
    for (int ksz = 2; ksz <= 1024; ksz <<= 1) {
        for (int j = ksz >> 1; j > 0; j >>= 1) {
            int l = t ^ j;
            if (l > t) {
                unsigned long long a = skey[t], c = skey[l];
                bool up = ((t & ksz) == 0);
                if (up ? (a > c) : (a < c)) { skey[t] = c; skey[l] = a; }
            }
            __syncthreads();
        }
    }
    if (t < k) {
        int idx = (int)(skey[t] & 0xFFFFFFFFu);
        int oldg = b * npg + idx;
        int newg = b * k + t;
        perm[newg] = oldg;
        gate[newg] = tanhf(score[oldg]);
        remap[oldg] = newg;
    } else if (t < npg) {
        int idx = (int)(skey[t] & 0xFFFFFFFFu);
        remap[b * npg + idx] = -1;
    }
}

// ---------------- gather new_x = h[perm] * gate (massively parallel) ----------------
__global__ void newx_kernel(const float* __restrict__ h, const int* __restrict__ perm,
                            const float* __restrict__ gate, float* __restrict__ xo) {
    int m = blockIdx.x * 4 + (threadIdx.x >> 6);
    int lane = threadIdx.x & 63;
    int old = perm[m];
    float g = gate[m];
    float2 v = ((const float2*)h)[old * 64 + lane];
    ((float2*)xo)[m * 64 + lane] = make_float2(v.x * g, v.y * g);
}

// ---------------- readout: rsum[b] (=|+=) [max over k ; mean over k] ----------------
__global__ __launch_bounds__(512) void readout_kernel(const float* __restrict__ x,
                                                      float* __restrict__ rsum, int k,
                                                      int first) {
    __shared__ float smx[4][128], ssm[4][128];
    int b = blockIdx.x, t = threadIdx.x;
    int f = t & 127, c = t >> 7;
    int rows = k >> 2;
    const float* base = x + (size_t)b * k * 128 + (size_t)c * rows * 128 + f;
    float mx = -INFINITY, sm = 0.f;
#pragma unroll 8
    for (int j = 0; j < rows; j++) {
        float v = base[(size_t)j * 128];
        mx = fmaxf(mx, v);
        sm += v;
    }
    smx[c][f] = mx;
    ssm[c][f] = sm;
    __syncthreads();
    if (c == 0) {
        float m2 = fmaxf(fmaxf(smx[0][f], smx[1][f]), fmaxf(smx[2][f], smx[3][f]));
        float s2 = (ssm[0][f] + ssm[1][f] + ssm[2][f] + ssm[3][f]) / (float)k;
        if (first) {
            rsum[b * 256 + f] = m2;
            rsum[b * 256 + 128 + f] = s2;
        } else {
            rsum[b * 256 + f] += m2;
            rsum[b * 256 + 128 + f] += s2;
        }
    }
}

// ---------------- per-graph edge compact (keeps per-graph segments) ----------------
__global__ __launch_bounds__(1024) void compact_kernel(
    const int* __restrict__ src, const int* __restrict__ dst,
    const int* __restrict__ gcntIn, int fixedIn, const int* __restrict__ remap,
    int* __restrict__ so, int* __restrict__ dd, int* __restrict__ gcntOut) {
    __shared__ int wsum[16];
    __shared__ int runbase;
    int g = blockIdx.x, t = threadIdx.x;
    int wave = t >> 6, lane = t & 63;
    int E = gcntIn ? gcntIn[g] : fixedIn;
    int ebase = g * ECAP;
    if (t == 0) runbase = 0;
    __syncthreads();
    for (int i0 = 0; i0 < E; i0 += 1024) {
        int i = i0 + t;
        bool v = false;
        int s = 0, d = 0;
        if (i < E) {
            s = remap[src[ebase + i]];
            d = remap[dst[ebase + i]];
            v = ((s | d) >= 0);
        }
        unsigned long long m = __ballot(v);
        int before = __popcll(m & ((1ULL << lane) - 1ULL));
        if (lane == 0) wsum[wave] = __popcll(m);
        __syncthreads();
        if (t == 0) {
            int tot = 0;
#pragma unroll
            for (int w2 = 0; w2 < 16; w2++) { int c = wsum[w2]; wsum[w2] = runbase + tot; tot += c; }
            runbase += tot;
        }
        __syncthreads();
        if (v) {
            int pos = ebase + wsum[wave] + before;
            so[pos] = s;
            dd[pos] = d;
        }
        __syncthreads();
    }
    if (t == 0) gcntOut[g] = runbase;
}

// ---------------- fused final MLP + log_softmax ----------------
__global__ void mlp_kernel(const float* __restrict__ rsum,
                           const float* __restrict__ w1, const float* __restrict__ b1,
                           const float* __restrict__ w2, const float* __restrict__ b2,
                           const float* __restrict__ w3, const float* __restrict__ b3,
                           float* __restrict__ out) {
    __shared__ float z0[256], z1l[128], z2l[64], lg[10], ls;
    int b = blockIdx.x, t = threadIdx.x;   // 128 threads
    z0[t] = rsum[b * 256 + t];
    z0[t + 128] = rsum[b * 256 + 128 + t];
    __syncthreads();
    float acc = b1[t];
    for (int k = 0; k < 256; k++) acc += z0[k] * w1[k * 128 + t];
    z1l[t] = fmaxf(acc, 0.f);
    __syncthreads();
    if (t < 64) {
        acc = b2[t];
        for (int k = 0; k < 128; k++) acc += z1l[k] * w2[k * 64 + t];
        z2l[t] = fmaxf(acc, 0.f);
    }
    __syncthreads();
    if (t < 10) {
        acc = b3[t];
        for (int k = 0; k < 64; k++) acc += z2l[k] * w3[k * 10 + t];
        lg[t] = acc;
    }
    __syncthreads();
    if (t == 0) {
        float mx = lg[0];
        for (int c = 1; c < 10; c++) mx = fmaxf(mx, lg[c]);
        float s = 0.f;
        for (int c = 0; c < 10; c++) s += expf(lg[c] - mx);
        ls = mx + logf(s);
    }
    __syncthreads();
    if (t < 10) out[b * 10 + t] = lg[t] - ls;
}

// =====================================================================
extern "C" void kernel_launch(void* const* d_in, const int* in_sizes, int n_in,
                              void* d_out, int out_size, void* d_ws, size_t ws_size,
                              hipStream_t stream) {
    char* ws = (char*)d_ws;
    size_t off = 0;
    auto alloc = [&](size_t bytes) -> void* {
        void* p = ws + off;
        off += (bytes + 255) & ~(size_t)255;
        return p;
    };
    float* hA = (float*)alloc(64000UL * 128 * 4);
    float* hB = (float*)alloc(64000UL * 128 * 4);
    float* score = (float*)alloc(64000UL * 4);
    float* dinvb = (float*)alloc(64000UL * 4);
    int2* rowdeg = (int2*)alloc(64000UL * 8);
    int2* edata = (int2*)alloc((size_t)EMAX * 8);
    int* srcA = (int*)alloc((size_t)EMAX * 4);
    int* dstA = (int*)alloc((size_t)EMAX * 4);
    int* srcB = (int*)alloc((size_t)EMAX * 4);
    int* dstB = (int*)alloc((size_t)EMAX * 4);
    int* perm = (int*)alloc(51200UL * 4);
    float* gate = (float*)alloc(51200UL * 4);
    int* remap = (int*)alloc(64000UL * 4);
    float* rsum = (float*)alloc(64UL * 256 * 4);
    _Float16* wsall = (_Float16*)alloc(9UL * 32768 * 2);
    float* pnorm = (float*)alloc(256);
    int* gA = (int*)alloc(256);
    int* gB = (int*)alloc(256);
    (void)ws_size;  // requires ~94 MB

    const float* x0 = (const float*)d_in[0];
    const int* src0 = (const int*)d_in[1];
    const int* dst0 = (const int*)d_in[2];

    pnorm3_kernel<<<3, 128, 0, stream>>>((const float*)d_in[27], (const float*)d_in[28],
                                         (const float*)d_in[29], pnorm);

    WP wp;
    wp.w[0] = (const float*)d_in[3];  wp.w[1] = (const float*)d_in[5];  wp.w[2] = (const float*)d_in[7];
    wp.w[3] = (const float*)d_in[9];  wp.w[4] = (const float*)d_in[11]; wp.w[5] = (const float*)d_in[13];
    wp.w[6] = (const float*)d_in[15]; wp.w[7] = (const float*)d_in[17]; wp.w[8] = (const float*)d_in[19];
    wsplit_kernel<<<9, 256, 0, stream>>>(wp, wsall);

    auto run_layer = [&](int n, int npg, int k, const float* x, int layer,
                         const int* esrc, const int* edst, const int* gcnt,
                         const float* ba, const float* bb, const float* bc,
                         const float* p, const float* pn,
                         int* so, int* ddst, int* gout) {
        build_kernel<<<BGR, 1024, 0, stream>>>(esrc, edst, gcnt, ECAP, npg,
                                               rowdeg, dinvb, edata);
        gemm3m_kernel<<<n / 64, 256, 0, stream>>>(x, wsall + (size_t)layer * 3 * 32768,
                                                  ba, bb, bc, hA);
        prop_t<0><<<n / 8, 256, 0, stream>>>(hA, hB, rowdeg, edata, dinvb,
                                             nullptr, nullptr, nullptr);
        prop_t<1><<<n / 8, 256, 0, stream>>>(hB, hA, rowdeg, edata, dinvb,
                                             p, pn, score);
        pool_kernel<<<BGR, 1024, 0, stream>>>(score, npg, k, perm, gate, remap);
        newx_kernel<<<(BGR * k) / 4, 256, 0, stream>>>(hA, perm, gate, hB);
        readout_kernel<<<BGR, 512, 0, stream>>>(hB, rsum, k, layer == 0 ? 1 : 0);
        if (gout)
            compact_kernel<<<BGR, 1024, 0, stream>>>(esrc, edst, gcnt, ECAP, remap,
                                                     so, ddst, gout);
    };

    run_layer(64000, 1000, 800, x0, 0, src0, dst0, nullptr,
              (const float*)d_in[4], (const float*)d_in[6], (const float*)d_in[8],
              (const float*)d_in[27], pnorm + 0, srcA, dstA, gA);

    run_layer(51200, 800, 640, hB, 1, srcA, dstA, gA,
              (const float*)d_in[10], (const float*)d_in[12], (const float*)d_in[14],
              (const float*)d_in[28], pnorm + 1, srcB, dstB, gB);

    run_layer(40960, 640, 512, hB, 2, srcB, dstB, gB,
              (const float*)d_in[16], (const float*)d_in[18], (const float*)d_in[20],
              (const float*)d_in[29], pnorm + 2, nullptr, nullptr, nullptr);

    mlp_kernel<<<64, 128, 0, stream>>>(rsum, (const float*)d_in[21], (const float*)d_in[22],
                                       (const float*)d_in[23], (const float*)d_in[24],
                                       (const float*)d_in[25], (const float*)d_in[26],
                                       (float*)d_out);
}

// Round 21
// 433.214 us; speedup vs baseline: 1.2351x; 1.0354x over previous
//
#include <hip/hip_runtime.h>
#include <hip/hip_bf16.h>
#include <math.h>

#define BGR 64
#define ECAP 16000
#define EMAX 1024000

typedef _Float16 f16x8 __attribute__((ext_vector_type(8)));
typedef float f32x4 __attribute__((ext_vector_type(4)));

// ---------------- pnorm x3 ----------------
__global__ __launch_bounds__(128) void pnorm3_kernel(const float* __restrict__ p1,
                              const float* __restrict__ p2,
                              const float* __restrict__ p3, float* __restrict__ out) {
    __shared__ float buf[128];
    int t = threadIdx.x, b = blockIdx.x;
    const float* p = (b == 0) ? p1 : (b == 1) ? p2 : p3;
    buf[t] = p[t] * p[t];
    __syncthreads();
    for (int off = 64; off; off >>= 1) {
        if (t < off) buf[t] += buf[t + off];
        __syncthreads();
    }
    if (t == 0) out[b] = sqrtf(buf[0]);
}

// ---------------- weight split: f32 [k][n] -> f16 hi/lo chunk-major ----------------
struct WP { const float* w[9]; };

__global__ void wsplit_kernel(WP wp, _Float16* __restrict__ out) {
    int mat = blockIdx.x;
    const float* __restrict__ w = wp.w[mat];
    _Float16* __restrict__ dst = out + (size_t)mat * 32768;
    for (int e = threadIdx.x; e < 2048; e += 256) {
        int n = e >> 4;
        int kb = (e & 15) * 8;
        f16x8 hi, lo;
#pragma unroll
        for (int j = 0; j < 8; j++) {
            float v = w[(kb + j) * 128 + n];
            _Float16 h = (_Float16)v;
            hi[j] = h;
            lo[j] = (_Float16)((v - (float)h) * 2048.0f);
        }
        int ks = kb >> 5, kg = (kb >> 3) & 3;
        *(f16x8*)(dst + ((((ks * 2 + 0) * 4 + kg) * 128 + n) * 8)) = hi;
        *(f16x8*)(dst + ((((ks * 2 + 1) * 4 + kg) * 128 + n) * 8)) = lo;
    }
}

// ---------------- per-graph CSR build: count + LDS scan + LDS-cursor scatter ----------
// Edge walks vectorized 4x (int4): 4 independent atomics/stores in flight per thread.
__global__ __launch_bounds__(1024) void build_kernel(
    const int* __restrict__ src, const int* __restrict__ dst,
    const int* __restrict__ gcnt, int fixedcnt, int npg,
    int2* __restrict__ rowdeg, float* __restrict__ dinv, int2* __restrict__ edata) {
    __shared__ int cnt[1024];
    __shared__ int scn[1024];
    __shared__ float sdinv[1024];
    int g = blockIdx.x, t = threadIdx.x;
    int E = gcnt ? gcnt[g] : fixedcnt;
    int ebase = g * ECAP;
    int gnb = g * npg;
    int E4 = E >> 2;
    const int4* dst4 = (const int4*)(dst + ebase);
    const int4* src4 = (const int4*)(src + ebase);

    cnt[t] = 0;
    __syncthreads();
    for (int i = t; i < E4; i += 1024) {
        int4 d4 = dst4[i];
        atomicAdd(&cnt[d4.x - gnb], 1);
        atomicAdd(&cnt[d4.y - gnb], 1);
        atomicAdd(&cnt[d4.z - gnb], 1);
        atomicAdd(&cnt[d4.w - gnb], 1);
    }
    for (int i = E4 * 4 + t; i < E; i += 1024)
        atomicAdd(&cnt[dst[ebase + i] - gnb], 1);
    __syncthreads();

    int myc = (t < npg) ? cnt[t] : 0;
    scn[t] = myc;
    __syncthreads();
    for (int off = 1; off < 1024; off <<= 1) {
        int v = (t >= off) ? scn[t - off] : 0;
        __syncthreads();
        scn[t] += v;
        __syncthreads();
    }
    int excl = scn[t] - myc;
    if (t < npg) {
        float dv = rsqrtf((float)myc + 1.0f);
        rowdeg[gnb + t] = make_int2(ebase + excl, myc);
        dinv[gnb + t] = dv;
        sdinv[t] = dv;
        scn[t] = excl;                    // becomes LDS cursor
    }
    __syncthreads();

    for (int i = t; i < E4; i += 1024) {
        int4 s4 = src4[i];
        int4 d4 = dst4[i];
        {
            int sl = s4.x - gnb, dl = d4.x - gnb;
            int pos = atomicAdd(&scn[dl], 1);
            edata[ebase + pos] = make_int2(s4.x, __float_as_int(sdinv[sl] * sdinv[dl]));
        }
        {
            int sl = s4.y - gnb, dl = d4.y - gnb;
            int pos = atomicAdd(&scn[dl], 1);
            edata[ebase + pos] = make_int2(s4.y, __float_as_int(sdinv[sl] * sdinv[dl]));
        }
        {
            int sl = s4.z - gnb, dl = d4.z - gnb;
            int pos = atomicAdd(&scn[dl], 1);
            edata[ebase + pos] = make_int2(s4.z, __float_as_int(sdinv[sl] * sdinv[dl]));
        }
        {
            int sl = s4.w - gnb, dl = d4.w - gnb;
            int pos = atomicAdd(&scn[dl], 1);
            edata[ebase + pos] = make_int2(s4.w, __float_as_int(sdinv[sl] * sdinv[dl]));
        }
    }
    for (int i = E4 * 4 + t; i < E; i += 1024) {
        int s = src[ebase + i];
        int d = dst[ebase + i];
        int sl = s - gnb, dl = d - gnb;
        int pos = atomicAdd(&scn[dl], 1);
        edata[ebase + pos] = make_int2(s, __float_as_int(sdinv[sl] * sdinv[dl]));
    }
}

// ---------------- fused 3-branch MFMA GEMM (f16 split, f32-equivalent accuracy) ----------
__global__ __launch_bounds__(256) void gemm3m_kernel(
    const float* __restrict__ x, const _Float16* __restrict__ wsp,
    const float* __restrict__ b0, const float* __restrict__ b1, const float* __restrict__ b2,
    float* __restrict__ out) {
    __shared__ _Float16 ws[2][16384] __attribute__((aligned(16)));
    const int tid = threadIdx.x;
    const int wave = tid >> 6;
    const int lane = tid & 63;
    const int l15 = lane & 15;
    const int kg = lane >> 4;          // 0..3
    const long base = (long)blockIdx.x * 64;
    const int m = wave * 16 + l15;     // row within block tile

    float4 xrow[8];
    const float4* xg = (const float4*)(x + (base + m) * 128);
#pragma unroll
    for (int q = 0; q < 8; q++) xrow[q] = xg[(q >> 1) * 8 + kg * 2 + (q & 1)];

    auto stageH = [&](int s, int buf) {
#pragma unroll
        for (int t = 0; t < 8; t++) {
            int u = tid + t * 256;
            __builtin_amdgcn_global_load_lds(
                (const __attribute__((address_space(1))) unsigned int*)(wsp + (size_t)s * 16384 + u * 8),
                (__attribute__((address_space(3))) unsigned int*)(&ws[buf][u * 8]),
                16, 0, 0);
        }
    };

    float tot[8][4];
#pragma unroll
    for (int nt = 0; nt < 8; nt++)
#pragma unroll
        for (int r = 0; r < 4; r++) tot[nt][r] = 0.f;

    f32x4 acc_h[8], acc_m[8];
    stageH(0, 0);

    for (int s = 0; s < 6; s++) {
        const int j = s >> 1;
        __syncthreads();
        if (s < 5) stageH(s + 1, (s & 1) ^ 1);

        if ((s & 1) == 0) {
#pragma unroll
            for (int nt = 0; nt < 8; nt++) {
                acc_h[nt] = (f32x4){0.f, 0.f, 0.f, 0.f};
                acc_m[nt] = (f32x4){0.f, 0.f, 0.f, 0.f};
            }
        }

        const _Float16* wbase = &ws[s & 1][0];
#pragma unroll
        for (int ksl = 0; ksl < 2; ksl++) {
            const int ks = (s & 1) * 2 + ksl;
            float ev[8] = {xrow[ks * 2].x, xrow[ks * 2].y, xrow[ks * 2].z, xrow[ks * 2].w,
                           xrow[ks * 2 + 1].x, xrow[ks * 2 + 1].y, xrow[ks * 2 + 1].z, xrow[ks * 2 + 1].w};
            f16x8 ah, al;
#pragma unroll
            for (int i = 0; i < 8; i++) {
                _Float16 h = (_Float16)ev[i];
                ah[i] = h;
                al[i] = (_Float16)((ev[i] - (float)h) * 2048.0f);
            }
            const _Float16* wb = wbase + ksl * 8192;
            const int nb = kg * 1024 + l15 * 8;
            f16x8 bh[8], bl[8];
#pragma unroll
            for (int nt = 0; nt < 8; nt++) {
                bh[nt] = *(const f16x8*)(wb + nb + nt * 128);
                bl[nt] = *(const f16x8*)(wb + 4096 + nb + nt * 128);
            }
#pragma unroll
            for (int nt = 0; nt < 8; nt++)
                acc_h[nt] = __builtin_amdgcn_mfma_f32_16x16x32_f16(ah, bh[nt], acc_h[nt], 0, 0, 0);
#pragma unroll
            for (int nt = 0; nt < 8; nt++)
                acc_m[nt] = __builtin_amdgcn_mfma_f32_16x16x32_f16(ah, bl[nt], acc_m[nt], 0, 0, 0);
#pragma unroll
            for (int nt = 0; nt < 8; nt++)
                acc_m[nt] = __builtin_amdgcn_mfma_f32_16x16x32_f16(al, bh[nt], acc_m[nt], 0, 0, 0);
        }

        if (s & 1) {
            const float* bb = (j == 0) ? b0 : (j == 1) ? b1 : b2;
#pragma unroll
            for (int nt = 0; nt < 8; nt++) {
                float bv = bb[nt * 16 + l15];
#pragma unroll
                for (int r = 0; r < 4; r++)
                    tot[nt][r] += fmaxf(acc_h[nt][r] + acc_m[nt][r] * (1.0f / 2048.0f) + bv, 0.f);
            }
        }
    }

    float* op = out + (base + wave * 16 + kg * 4) * 128 + l15;
#pragma unroll
    for (int nt = 0; nt < 8; nt++)
#pragma unroll
        for (int r = 0; r < 4; r++) op[r * 128 + nt * 16] = tot[nt][r];
}

// ---------------- propagation (+optional fused score) ----------------
// Half-wave per node (float4/lane): 32 edges in flight per wave (MLP-optimal).
template <int SC>
__global__ __launch_bounds__(256, 4) void prop_t(
    const float* __restrict__ hin, float* __restrict__ hout,
    const int2* __restrict__ rowdeg, const int2* __restrict__ edata,
    const float* __restrict__ dinv,
    const float* __restrict__ p, const float* __restrict__ pn, float* __restrict__ score) {
    int per = gridDim.x >> 3;
    int b = blockIdx.x;
    int sb = (b & 7) * per + (b >> 3);          // XCD swizzle
    int wave = threadIdx.x >> 6;
    int lane = threadIdx.x & 63;
    int half = lane >> 5;
    int l31 = lane & 31;
    int node = sb * 8 + wave * 2 + half;
    int pbase = (lane & 32) << 2;               // bpermute byte base: half*128

    const char* hb = (const char*)hin;
    const unsigned loff = (unsigned)l31 * 16u;

    float4 hv = *(const float4*)(hb + (size_t)node * 512 + loff);
    float di = dinv[node];
    float selfc = 1.0f + di * di;
    float ax = hv.x * selfc, ay = hv.y * selfc, az = hv.z * selfc, aw = hv.w * selfc;

    int2 rd = rowdeg[node];
    int e0 = rd.x;
    int dg = rd.y;
    int e1 = e0 + dg;
    int degA = __builtin_amdgcn_readlane(dg, 0);
    int degB = __builtin_amdgcn_readlane(dg, 32);
    int dmax = degA > degB ? degA : degB;
    int T = (dmax + 15) >> 4;

    for (int t = 0; t < T; ++t) {
        int ee = e0 + t * 16 + (lane & 15);
        int ec = ee < e1 - 1 ? ee : e1 - 1;
        ec = ec < e0 ? e0 : ec;
        int2 md = edata[ec];
        bool val = ee < e1;
        int ci = val ? md.x : 0;
        int wi = val ? md.y : 0;
        float4 g[16];
        float w[16];
#pragma unroll
        for (int j = 0; j < 16; ++j) {
            int idx = __builtin_amdgcn_ds_bpermute(pbase + j * 4, ci);
            int wj = __builtin_amdgcn_ds_bpermute(pbase + j * 4, wi);
            w[j] = __int_as_float(wj);
            g[j] = *(const float4*)(hb + (unsigned)idx * 512u + loff);
        }
        __builtin_amdgcn_sched_barrier(0);
#pragma unroll
        for (int j = 0; j < 16; ++j) {
            ax += w[j] * g[j].x;
            ay += w[j] * g[j].y;
            az += w[j] * g[j].z;
            aw += w[j] * g[j].w;
        }
    }

    *(float4*)((char*)hout + (size_t)node * 512 + loff) = make_float4(ax, ay, az, aw);

    if (SC) {
        float4 pv = ((const float4*)p)[l31];
        float v = ax * pv.x + ay * pv.y + az * pv.z + aw * pv.w;
        v += __shfl_xor(v, 16);
        v += __shfl_xor(v, 8);
        v += __shfl_xor(v, 4);
        v += __shfl_xor(v, 2);
        v += __shfl_xor(v, 1);
        if (l31 == 0) score[node] = v / pn[0];
    }
}

// ---------------- top-k pool: 1024-thread key-packed bitonic sort ----------------
__global__ __launch_bounds__(1024) void pool_kernel(const float* __restrict__ score, int npg, int k,
                            int* __restrict__ perm, float* __restrict__ gate,
                            int* __restrict__ remap) {
    __shared__ unsigned long long skey[1024];
    int b = blockIdx.x, t = threadIdx.x;
    float v = (t < npg) ? score[b * npg + t] : -INFINITY;
    unsigned ub = __float_as_uint(v);
    unsigned asc = ub ^ ((ub >> 31) ? 0xFFFFFFFFu : 0x80000000u);  // ascending uint map
    unsigned desc = ~asc;                                          // descending
    skey[t] = ((unsigned long long)desc << 32) | (unsigned)t;
    __syncthreads();
    for (int ksz = 2; ksz <= 1024; ksz <<= 1) {
        for (int j = ksz >> 1; j > 0; j >>= 1) {
            int l = t ^ j;
            if (l > t) {
                unsigned long long a = skey[t], c = skey[l];
                bool up = ((t & ksz) == 0);
                if (up ? (a > c) : (a < c)) { skey[t] = c; skey[l] = a; }
            }
            __syncthreads();
        }
    }
    if (t < k) {
        int idx = (int)(skey[t] & 0xFFFFFFFFu);
        int oldg = b * npg + idx;
        int newg = b * k + t;
        perm[newg] = oldg;
        gate[newg] = tanhf(score[oldg]);
        remap[oldg] = newg;
    } else if (t < npg) {
        int idx = (int)(skey[t] & 0xFFFFFFFFu);
        remap[b * npg + idx] = -1;
    }
}

// ---------------- gather new_x = h[perm] * gate (massively parallel) ----------------
__global__ void newx_kernel(const float* __restrict__ h, const int* __restrict__ perm,
                            const float* __restrict__ gate, float* __restrict__ xo) {
    int m = blockIdx.x * 4 + (threadIdx.x >> 6);
    int lane = threadIdx.x & 63;
    int old = perm[m];
    float g = gate[m];
    float2 v = ((const float2*)h)[old * 64 + lane];
    ((float2*)xo)[m * 64 + lane] = make_float2(v.x * g, v.y * g);
}

// ---------------- readout: rsum[b] (=|+=) [max over k ; mean over k] ----------------
__global__ __launch_bounds__(512) void readout_kernel(const float* __restrict__ x,
                                                      float* __restrict__ rsum, int k,
                                                      int first) {
    __shared__ float smx[4][128], ssm[4][128];
    int b = blockIdx.x, t = threadIdx.x;
    int f = t & 127, c = t >> 7;
    int rows = k >> 2;
    const float* base = x + (size_t)b * k * 128 + (size_t)c * rows * 128 + f;
    float mx = -INFINITY, sm = 0.f;
#pragma unroll 8
    for (int j = 0; j < rows; j++) {
        float v = base[(size_t)j * 128];
        mx = fmaxf(mx, v);
        sm += v;
    }
    smx[c][f] = mx;
    ssm[c][f] = sm;
    __syncthreads();
    if (c == 0) {
        float m2 = fmaxf(fmaxf(smx[0][f], smx[1][f]), fmaxf(smx[2][f], smx[3][f]));
        float s2 = (ssm[0][f] + ssm[1][f] + ssm[2][f] + ssm[3][f]) / (float)k;
        if (first) {
            rsum[b * 256 + f] = m2;
            rsum[b * 256 + 128 + f] = s2;
        } else {
            rsum[b * 256 + f] += m2;
            rsum[b * 256 + 128 + f] += s2;
        }
    }
}

// ---------------- per-graph edge compact (keeps per-graph segments) ----------------
__global__ __launch_bounds__(1024) void compact_kernel(
    const int* __restrict__ src, const int* __restrict__ dst,
    const int* __restrict__ gcntIn, int fixedIn, const int* __restrict__ remap,
    int* __restrict__ so, int* __restrict__ dd, int* __restrict__ gcntOut) {
    __shared__ int wsum[16];
    __shared__ int runbase;
    int g = blockIdx.x, t = threadIdx.x;
    int wave = t >> 6, lane = t & 63;
    int E = gcntIn ? gcntIn[g] : fixedIn;
    int ebase = g * ECAP;
    if (t == 0) runbase = 0;
    __syncthreads();
    for (int i0 = 0; i0 < E; i0 += 1024) {
        int i = i0 + t;
        bool v = false;
        int s = 0, d = 0;
        if (i < E) {
            s = remap[src[ebase + i]];
            d = remap[dst[ebase + i]];
            v = ((s | d) >= 0);
        }
        unsigned long long m = __ballot(v);
        int before = __popcll(m & ((1ULL << lane) - 1ULL));
        if (lane == 0) wsum[wave] = __popcll(m);
        __syncthreads();
        if (t == 0) {
            int tot = 0;
#pragma unroll
            for (int w2 = 0; w2 < 16; w2++) { int c = wsum[w2]; wsum[w2] = runbase + tot; tot += c; }
            runbase += tot;
        }
        __syncthreads();
        if (v) {
            int pos = ebase + wsum[wave] + before;
            so[pos] = s;
            dd[pos] = d;
        }
        __syncthreads();
    }
    if (t == 0) gcntOut[g] = runbase;
}

// ---------------- fused final MLP + log_softmax ----------------
__global__ void mlp_kernel(const float* __restrict__ rsum,
                           const float* __restrict__ w1, const float* __restrict__ b1,
                           const float* __restrict__ w2, const float* __restrict__ b2,
                           const float* __restrict__ w3, const float* __restrict__ b3,
                           float* __restrict__ out) {
    __shared__ float z0[256], z1l[128], z2l[64], lg[10], ls;
    int b = blockIdx.x, t = threadIdx.x;   // 128 threads
    z0[t] = rsum[b * 256 + t];
    z0[t + 128] = rsum[b * 256 + 128 + t];
    __syncthreads();
    float acc = b1[t];
    for (int k = 0; k < 256; k++) acc += z0[k] * w1[k * 128 + t];
    z1l[t] = fmaxf(acc, 0.f);
    __syncthreads();
    if (t < 64) {
        acc = b2[t];
        for (int k = 0; k < 128; k++) acc += z1l[k] * w2[k * 64 + t];
        z2l[t] = fmaxf(acc, 0.f);
    }
    __syncthreads();
    if (t < 10) {
        acc = b3[t];
        for (int k = 0; k < 64; k++) acc += z2l[k] * w3[k * 10 + t];
        lg[t] = acc;
    }
    __syncthreads();
    if (t == 0) {
        float mx = lg[0];
        for (int c = 1; c < 10; c++) mx = fmaxf(mx, lg[c]);
        float s = 0.f;
        for (int c = 0; c < 10; c++) s += expf(lg[c] - mx);
        ls = mx + logf(s);
    }
    __syncthreads();
    if (t < 10) out[b * 10 + t] = lg[t] - ls;
}

// =====================================================================
extern "C" void kernel_launch(void* const* d_in, const int* in_sizes, int n_in,
                              void* d_out, int out_size, void* d_ws, size_t ws_size,
                              hipStream_t stream) {
    char* ws = (char*)d_ws;
    size_t off = 0;
    auto alloc = [&](size_t bytes) -> void* {
        void* p = ws + off;
        off += (bytes + 255) & ~(size_t)255;
        return p;
    };
    float* hA = (float*)alloc(64000UL * 128 * 4);
    float* hB = (float*)alloc(64000UL * 128 * 4);
    float* score = (float*)alloc(64000UL * 4);
    float* dinvb = (float*)alloc(64000UL * 4);
    int2* rowdeg = (int2*)alloc(64000UL * 8);
    int2* edata = (int2*)alloc((size_t)EMAX * 8);
    int* srcA = (int*)alloc((size_t)EMAX * 4);
    int* dstA = (int*)alloc((size_t)EMAX * 4);
    int* srcB = (int*)alloc((size_t)EMAX * 4);
    int* dstB = (int*)alloc((size_t)EMAX * 4);
    int* perm = (int*)alloc(51200UL * 4);
    float* gate = (float*)alloc(51200UL * 4);
    int* remap = (int*)alloc(64000UL * 4);
    float* rsum = (float*)alloc(64UL * 256 * 4);
    _Float16* wsall = (_Float16*)alloc(9UL * 32768 * 2);
    float* pnorm = (float*)alloc(256);
    int* gA = (int*)alloc(256);
    int* gB = (int*)alloc(256);
    (void)ws_size;  // requires ~94 MB

    const float* x0 = (const float*)d_in[0];
    const int* src0 = (const int*)d_in[1];
    const int* dst0 = (const int*)d_in[2];

    pnorm3_kernel<<<3, 128, 0, stream>>>((const float*)d_in[27], (const float*)d_in[28],
                                         (const float*)d_in[29], pnorm);

    WP wp;
    wp.w[0] = (const float*)d_in[3];  wp.w[1] = (const float*)d_in[5];  wp.w[2] = (const float*)d_in[7];
    wp.w[3] = (const float*)d_in[9];  wp.w[4] = (const float*)d_in[11]; wp.w[5] = (const float*)d_in[13];
    wp.w[6] = (const float*)d_in[15]; wp.w[7] = (const float*)d_in[17]; wp.w[8] = (const float*)d_in[19];
    wsplit_kernel<<<9, 256, 0, stream>>>(wp, wsall);

    auto run_layer = [&](int n, int npg, int k, const float* x, int layer,
                         const int* esrc, const int* edst, const int* gcnt,
                         const float* ba, const float* bb, const float* bc,
                         const float* p, const float* pn,
                         int* so, int* ddst, int* gout) {
        build_kernel<<<BGR, 1024, 0, stream>>>(esrc, edst, gcnt, ECAP, npg,
                                               rowdeg, dinvb, edata);
        gemm3m_kernel<<<n / 64, 256, 0, stream>>>(x, wsall + (size_t)layer * 3 * 32768,
                                                  ba, bb, bc, hA);
        prop_t<0><<<n / 8, 256, 0, stream>>>(hA, hB, rowdeg, edata, dinvb,
                                             nullptr, nullptr, nullptr);
        prop_t<1><<<n / 8, 256, 0, stream>>>(hB, hA, rowdeg, edata, dinvb,
                                             p, pn, score);
        pool_kernel<<<BGR, 1024, 0, stream>>>(score, npg, k, perm, gate, remap);
        newx_kernel<<<(BGR * k) / 4, 256, 0, stream>>>(hA, perm, gate, hB);
        readout_kernel<<<BGR, 512, 0, stream>>>(hB, rsum, k, layer == 0 ? 1 : 0);
        if (gout)
            compact_kernel<<<BGR, 1024, 0, stream>>>(esrc, edst, gcnt, ECAP, remap,
                                                     so, ddst, gout);
    };

    run_layer(64000, 1000, 800, x0, 0, src0, dst0, nullptr,
              (const float*)d_in[4], (const float*)d_in[6], (const float*)d_in[8],
              (const float*)d_in[27], pnorm + 0, srcA, dstA, gA);

    run_layer(51200, 800, 640, hB, 1, srcA, dstA, gA,
              (const float*)d_in[10], (const float*)d_in[12], (const float*)d_in[14],
              (const float*)d_in[28], pnorm + 1, srcB, dstB, gB);

    run_layer(40960, 640, 512, hB, 2, srcB, dstB, gB,
              (const float*)d_in[16], (const float*)d_in[18], (const float*)d_in[20],
              (const float*)d_in[29], pnorm + 2, nullptr, nullptr, nullptr);

    mlp_kernel<<<64, 128, 0, stream>>>(rsum, (const float*)d_in[21], (const float*)d_in[22],
                                       (const float*)d_in[23], (const float*)d_in[24],
                                       (const float*)d_in[25], (const float*)d_in[26],
                                       (float*)d_out);
}